// Round 12
// baseline (105.940 us; speedup 1.0000x reference)
//
#include <hip/hip_runtime.h>

#define NB    2000
#define NT    365
#define LENF  15
#define CH    8                 // steps per chunk
#define NCHF  45                // full chunks; chunk 45 = 5-step tail
#define WPS   192               // LDS words per step (16 records x 12)
#define WPC   (CH * WPS)        // 1536 words per chunk buffer
#define BB    140160            // bytes per basin in params (365*96*4)

#define EXP2F(x) __builtin_amdgcn_exp2f(x)
#define LOG2F(x) __builtin_amdgcn_logf(x)
#define LOG2E    1.44269504088896f

#define GLD4(g, l) __builtin_amdgcn_global_load_lds( \
    (const __attribute__((address_space(1))) void*)(g), \
    (__attribute__((address_space(3))) void*)(l), 4, 0, 0)

// DPP cross-lane ops — pure VALU, no LDS pipe, no lgkmcnt.
template <int CTRL>
__device__ __forceinline__ float dpp_mov(float x) {
  int xi = __float_as_int(x);
  int r  = __builtin_amdgcn_update_dpp(xi, xi, CTRL, 0xF, 0xF, true);
  return __int_as_float(r);
}
#define DPP_XOR1   0xB1    // quad_perm [1,0,3,2]
#define DPP_XOR2   0x4E    // quad_perm [2,3,0,1]
#define DPP_HMIRR  0x141   // row_half_mirror: i <-> 7-i within each 8-lane half

// TWO BASINS PER WAVE (bsel=(lane>>3)&1, m=lane&7; lanes 16-63 duplicate).
// R6-R11 triangulated the limiter to per-wave serial fetch cost per step
// (~12 reads x issue+latency with ~1 wave/SIMD). This version stages a
// TRANSPOSED record layout via scatter global_load_lds (per-lane global
// source, linear LDS dst): record(s,bsel,m) = 48B = [9 params, P, Ep, T].
// Hot loop: 3 ds_read_b128 + 3 GLD4 per step. Record stride 48B -> 2-way
// bank aliasing (free). Depth-2 chunk pipeline, vmcnt(24).
__global__ __launch_bounds__(64) void prms_kernel(
    const float* __restrict__ P, const float* __restrict__ Ep,
    const float* __restrict__ Tair, const float* __restrict__ params,
    const float* __restrict__ rout_a, const float* __restrict__ rout_b,
    float* __restrict__ out)
{
  __shared__ __attribute__((aligned(16))) float sh[2][WPC];  // 12288 B
  __shared__ float Qs[2][NT + 3];                            //  2944 B

  const int lane = threadIdx.x;       // 0..63
  const int m    = lane & 7;
  const int bsel = (lane >> 3) & 1;
  const int b0   = blockIdx.x * 2;

  const float ra0 = rout_a[b0],     rb0 = rout_b[b0];
  const float ra1 = rout_a[b0 + 1], rb1 = rout_b[b0 + 1];

  // ---- per-lane scatter-staging source pointers (computed once) ----
  // GLD4 #(3j+e) fills LDS words j*192 + e*64 + lane. Word u = e*64+lane of a
  // step maps to record r16 = u/12 (= bsel*8+m), field k = u%12:
  // k 0..8 -> params pr{0,1,3,4,5,6,8,9,10} (stride 384 B/step),
  // k 9/10/11 -> P/Ep/Tair (stride 4 B/step).
  const char* V0; const char* V1; const char* V2;
  int St0, St1, St2;
  {
    const char* v[3]; int st[3];
    #pragma unroll
    for (int e = 0; e < 3; ++e) {
      const int u   = e * 64 + lane;
      const int r16 = (u * 171) >> 11;        // u/12, exact for u<192
      const int k   = u - r16 * 12;
      const int bs  = r16 >> 3;
      const int mm  = r16 & 7;
      if (k <= 8) {
        const int pk = k + (k >= 2) + (k >= 6);   // {0,1,3,4,5,6,8,9,10}
        v[e]  = (const char*)params + (size_t)(b0 + bs) * BB + pk * 32 + mm * 4;
        st[e] = 384;
      } else {
        const float* arr = (k == 9) ? P : (k == 10) ? Ep : Tair;
        v[e]  = (const char*)(arr + (size_t)(b0 + bs) * NT);
        st[e] = 4;
      }
    }
    V0 = v[0]; V1 = v[1]; V2 = v[2];
    St0 = st[0]; St1 = st[1]; St2 = st[2];
  }

  int tg = 0;   // global step index of next staged step (uniform)
  auto ISSUE = [&](int buf) {
    #pragma unroll
    for (int j = 0; j < CH; ++j) {
      GLD4(V0, &sh[buf][j * WPS]);
      GLD4(V1, &sh[buf][j * WPS + 64]);
      GLD4(V2, &sh[buf][j * WPS + 128]);
      if (tg < NT - 1) { V0 += St0; V1 += St1; V2 += St2; }  // freeze at t=364
      ++tg;
    }
  };

  float S1 = 0.5f, S2 = 0.5f, S3 = 0.5f, S4 = 0.5f, S5 = 0.5f;
  const int rbase = (bsel * 8 + m) * 12;   // word offset of this thread's record

  auto STEPD = [&](float4 x0, float4 x1, float4 x2, int t) {
    const float tt    = fmaf(x0.x, 8.0f, -3.0f);
    const float ddf   = x0.y * 20.0f;
    const float Smax3 = fmaf(x0.z, 680.0f, 20.0f);
    const float p_lo  = fmaf(x0.w, 0.99f, 0.005f);
    const float p_hi  = fmaf(x1.x, 0.99f, 0.005f);
    const float p_exp = fmaf(x1.y, 4.0f, 1.0f);
    const float i1    = x1.z;
    const float i2    = x1.w * 0.001f;
    const float kb    = x2.x;
    const float Pt    = x2.y;
    const float Ept   = x2.z;
    const float Tt    = x2.w;

    const float snow = (Tt <= tt) ? Pt : 0.0f;
    const float rain = Pt - snow;
    const float melt = fmaxf(fminf(ddf * (Tt - tt), S1), 0.0f);   // DT=1
    S1 = S1 + snow - melt;

    const float inter = rain * 0.95f;
    const float evap2 = fminf(S2, Ept);
    S2 = fmaxf(S2 + (rain - inter) - evap2, 0.0f);

    const float infil  = melt + inter;
    const float frac   = fmaxf(S3, 0.0f) * __builtin_amdgcn_rcpf(Smax3);
    const float satexc = (p_lo + (p_hi - p_lo) * frac) * infil;
    const float rem    = fmaxf(infil - satexc, 0.0f);
    // frac^p_exp: frac==0 -> log2=-inf -> exp2(-inf)=0 (matches 0**p, p>=1)
    const float rech   = rem * EXP2F(p_exp * LOG2F(frac));
    const float evap3  = fminf(frac * Ept, S3);
    S3 = S3 + rem - rech - evap3;

    const float S4c   = fmaxf(S4, 0.0f);
    const float iflow = fminf(S4c, fmaf(i2, S4c * S4c, i1 * S4c));
    S4 = S4 + rech - iflow;

    const float base = kb * S5;
    S5 = S5 + iflow - base;

    float q = satexc + base;
    q += dpp_mov<DPP_XOR1>(q);
    q += dpp_mov<DPP_XOR2>(q);
    q += dpp_mov<DPP_HMIRR>(q);
    if ((lane & 55) == 0)                // m==0 && dup==0: lanes 0 and 8
      Qs[bsel][t] = q * 0.125f;
  };

  // ---- depth-2 chunk pipeline; 1-step float4 ping-pong inside ----
  ISSUE(0);
  ISSUE(1);
  for (int c = 0; c < NCHF; ++c) {
    asm volatile("s_waitcnt vmcnt(24)" ::: "memory");   // chunk c resident (c+1 in flight)
    const int buf = c & 1;
    const int t0  = c * CH;
    const float4* rp = (const float4*)&sh[buf][rbase];  // step s at rp[s*48 + {0,1,2}]
    float4 a0, a1, a2, c0, c1, c2;
    a0 = rp[0]; a1 = rp[1]; a2 = rp[2];
    #pragma unroll
    for (int s = 0; s < CH; ++s) {
      if ((s & 1) == 0) {
        if (s < CH - 1) { c0 = rp[(s+1)*48]; c1 = rp[(s+1)*48+1]; c2 = rp[(s+1)*48+2]; }
        STEPD(a0, a1, a2, t0 + s);
      } else {
        if (s < CH - 1) { a0 = rp[(s+1)*48]; a1 = rp[(s+1)*48+1]; a2 = rp[(s+1)*48+2]; }
        STEPD(c0, c1, c2, t0 + s);
      }
    }
    asm volatile("s_waitcnt lgkmcnt(0)" ::: "memory");  // reads of buf drained
    if (c <= NCHF - 2) ISSUE(buf);                      // stages chunks 2..45
  }
  // ---- tail chunk 45: t = 360..364 (5 steps, buf 1) ----
  asm volatile("s_waitcnt vmcnt(0)" ::: "memory");
  {
    const float4* rp = (const float4*)&sh[1][rbase];
    float4 a0, a1, a2, c0, c1, c2;
    a0 = rp[0]; a1 = rp[1]; a2 = rp[2];
    #pragma unroll
    for (int s = 0; s < 5; ++s) {
      if ((s & 1) == 0) {
        if (s < 4) { c0 = rp[(s+1)*48]; c1 = rp[(s+1)*48+1]; c2 = rp[(s+1)*48+2]; }
        STEPD(a0, a1, a2, 360 + s);
      } else {
        if (s < 4) { a0 = rp[(s+1)*48]; a1 = rp[(s+1)*48+1]; a2 = rp[(s+1)*48+2]; }
        STEPD(c0, c1, c2, 360 + s);
      }
    }
  }

  __syncthreads();

  // ---- fused gamma routing conv, per basin (all 64 lanes) ----
  #pragma unroll
  for (int bs = 0; bs < 2; ++bs) {
    const float ra_v = bs ? ra1 : ra0;
    const float rb_v = bs ? rb1 : rb0;
    const float aa  = fmaxf(ra_v * 2.9f, 0.0f) + 0.1f;
    const float th  = fmaxf(rb_v * 6.5f, 0.0f) + 0.5f;
    const float am1 = aa - 1.0f;
    const float ith = -LOG2E / th;

    float w[LENF];
    float wsum = 0.0f;
    #pragma unroll
    for (int j = 0; j < LENF; ++j) {
      const float tj = (float)j + 0.5f;
      w[j] = EXP2F(fmaf(am1, LOG2F(tj), tj * ith));
      wsum += w[j];
    }
    const float inv = 1.0f / wsum;
    #pragma unroll
    for (int j = 0; j < LENF; ++j) w[j] *= inv;

    float* __restrict__ ob = out + (size_t)(b0 + bs) * NT;
    #pragma unroll
    for (int k = 0; k < 6; ++k) {
      const int t = lane + k * 64;
      if (t < NT) {
        float acc = 0.0f;
        #pragma unroll
        for (int j = 0; j < LENF; ++j) {
          const int idx = t - j;
          if (idx >= 0) acc += w[j] * Qs[bs][idx];
        }
        ob[t] = acc;
      }
    }
  }
}

extern "C" void kernel_launch(void* const* d_in, const int* in_sizes, int n_in,
                              void* d_out, int out_size, void* d_ws, size_t ws_size,
                              hipStream_t stream) {
  const float* P      = (const float*)d_in[0];
  const float* Ep     = (const float*)d_in[1];
  const float* Tair   = (const float*)d_in[2];
  const float* params = (const float*)d_in[3];
  const float* ra     = (const float*)d_in[4];
  const float* rb     = (const float*)d_in[5];
  float* out = (float*)d_out;

  prms_kernel<<<NB / 2, 64, 0, stream>>>(P, Ep, Tair, params, ra, rb, out);
}

// Round 13
// 83.221 us; speedup vs baseline: 1.2730x; 1.2730x over previous
//
#include <hip/hip_runtime.h>

#define NB      2000
#define NT      365
#define LENF    15
#define PSTRIDE 96              // 12 params * 8 muls, floats per (b,t)
#define CH      16              // timesteps per chunk
#define NFULL   22              // full chunks (352 steps)
#define NCHUNK  23              // incl. 13-step tail
#define CHBYTES (CH * PSTRIDE * 4)              // 6144 B per chunk per basin
#define BASIN_BYTES (NT * PSTRIDE * 4)          // 140160
#define CLAMP16     (BASIN_BYTES - 16)          // 140144
#define PARW    1544            // LDS words per basin param block (1536 + 8 pad; 1544%32==8)
#define FRCW    72              // LDS words per basin forcing block (64 + pad; 72%32==8)
// VMEM ops per ISSUE = 12 GLD16 + 2 GLD4 = 14 -> main-loop wait is vmcnt(14)

#define GLD16(g, l) __builtin_amdgcn_global_load_lds( \
    (const __attribute__((address_space(1))) void*)(g), \
    (__attribute__((address_space(3))) void*)(l), 16, 0, 0)
#define GLD4(g, l) __builtin_amdgcn_global_load_lds( \
    (const __attribute__((address_space(1))) void*)(g), \
    (__attribute__((address_space(3))) void*)(l), 4, 0, 0)

#define EXP2F(x) __builtin_amdgcn_exp2f(x)
#define LOG2F(x) __builtin_amdgcn_logf(x)
#define LOG2E    1.44269504088896f

// DPP cross-lane ops — pure VALU, no LDS pipe, no lgkmcnt.
template <int CTRL>
__device__ __forceinline__ float dpp_mov(float x) {
  int xi = __float_as_int(x);
  int r  = __builtin_amdgcn_update_dpp(xi, xi, CTRL, 0xF, 0xF, true);
  return __int_as_float(r);
}
#define DPP_XOR1   0xB1    // quad_perm [1,0,3,2]
#define DPP_XOR2   0x4E    // quad_perm [2,3,0,1]
#define DPP_HMIRR  0x141   // row_half_mirror: i <-> 7-i within each 8-lane half

// TWO BASINS PER WAVE (lane = d*16 + bsel*8 + m), 1000 blocks -> ~4 waves/CU.
// R13 = R8 (best, 80.7us) with ONE change: the 4-step/48-read register batch
// is replaced by a 1-step ping-pong (12 reads <= lgkmcnt's 4-bit max 15), so
// the compiler can emit lgkmcnt(12) and step s+1's ds_reads retire under
// STEPD(s)'s VALU stream. R8's 48-read batches forced drains to <=15,
// serializing the LDS round-trip per batch (R10 tested this confounded with
// a wave-count change). Everything else identical to R8.
__global__ __launch_bounds__(64) void prms_kernel(
    const float* __restrict__ P, const float* __restrict__ Ep,
    const float* __restrict__ Tair, const float* __restrict__ params,
    const float* __restrict__ rout_a, const float* __restrict__ rout_b,
    float* __restrict__ out)
{
  __shared__ __attribute__((aligned(16))) float sh_par[2][2 * PARW];  // 24704 B
  __shared__ __attribute__((aligned(16))) float sh_frc[2][2][FRCW];   //  1152 B
  __shared__ float Qs[2][NT + 3];                                     //  2944 B

  const int lane = threadIdx.x;        // 0..63
  const int m    = lane & 7;           // mul index
  const int bsel = (lane >> 3) & 1;    // which of the wave's 2 basins
  const int b0   = blockIdx.x * 2;     // first basin of this block

  // preload routing params early — latency hidden under the scan
  const float ra0 = rout_a[b0],     rb0 = rout_b[b0];
  const float ra1 = rout_a[b0 + 1], rb1 = rout_b[b0 + 1];

  const char* pbg[2] = {
    (const char*)(params + (size_t)b0 * (NT * PSTRIDE)),
    (const char*)(params + (size_t)(b0 + 1) * (NT * PSTRIDE)) };

  // forcing source for the GLD4s: lane -> (arr = lane>>4 clamped, s = lane&15)
  const int farr = (lane >> 4) > 2 ? 2 : (lane >> 4);
  const int fs   = lane & 15;
  const float* fsrcs[2][3] = {
    { P + (size_t)b0 * NT,       Ep + (size_t)b0 * NT,       Tair + (size_t)b0 * NT },
    { P + (size_t)(b0 + 1) * NT, Ep + (size_t)(b0 + 1) * NT, Tair + (size_t)(b0 + 1) * NT } };

  // ---- staging: 12x GLD16 (params) + 2x GLD4 (forcings) per chunk ----
  auto ISSUE = [&](int c, int buf) {
    #pragma unroll
    for (int bs = 0; bs < 2; ++bs) {
      #pragma unroll
      for (int j = 0; j < 6; ++j) {
        int off = c * CHBYTES + j * 1024 + lane * 16;
        off = off > CLAMP16 ? CLAMP16 : off;   // tail clamp (dups land in pad)
        GLD16(pbg[bs] + off, &sh_par[buf][bs * PARW + j * 256]);
      }
    }
    #pragma unroll
    for (int bs = 0; bs < 2; ++bs) {
      int ft = c * CH + fs;
      ft = ft > NT - 1 ? NT - 1 : ft;
      GLD4(fsrcs[bs][farr] + ft, &sh_frc[buf][bs][0]);
    }
  };

  float S1 = 0.5f, S2 = 0.5f, S3 = 0.5f, S4 = 0.5f, S5 = 0.5f;
  const int pbase = bsel * PARW + m;    // thread-const param word base
  const int fbb   = bsel * FRCW;        // thread-const forcing base

  // ---- per-step LDS->register load: 12 values, static indices ----
  auto LOADR = [&](int buf, int s, float* r) {
    const float* par = &sh_par[buf][pbase + s * PSTRIDE];
    r[0] = par[0];   r[1] = par[8];   r[2] = par[24];
    r[3] = par[32];  r[4] = par[40];  r[5] = par[48];
    r[6] = par[64];  r[7] = par[72];  r[8] = par[80];
    const float* f = &sh_frc[buf][0][fbb];
    r[9]  = f[s];
    r[10] = f[16 + s];
    r[11] = f[32 + s];
  };

  auto STEPD = [&](const float* d, int t) {
    const float tt    = fmaf(d[0], 8.0f, -3.0f);
    const float ddf   = d[1] * 20.0f;
    const float Smax3 = fmaf(d[2], 680.0f, 20.0f);
    const float p_lo  = fmaf(d[3], 0.99f, 0.005f);
    const float p_hi  = fmaf(d[4], 0.99f, 0.005f);
    const float p_exp = fmaf(d[5], 4.0f, 1.0f);
    const float i1    = d[6];
    const float i2    = d[7] * 0.001f;
    const float kb    = d[8];
    const float Pt    = d[9];
    const float Ept   = d[10];
    const float Tt    = d[11];

    const float snow = (Tt <= tt) ? Pt : 0.0f;
    const float rain = Pt - snow;
    const float melt = fmaxf(fminf(ddf * (Tt - tt), S1), 0.0f);   // DT=1
    S1 = S1 + snow - melt;

    const float inter = rain * 0.95f;
    const float evap2 = fminf(S2, Ept);
    S2 = fmaxf(S2 + (rain - inter) - evap2, 0.0f);

    const float infil  = melt + inter;
    const float frac   = fmaxf(S3, 0.0f) * __builtin_amdgcn_rcpf(Smax3);
    const float satexc = (p_lo + (p_hi - p_lo) * frac) * infil;
    const float rem    = fmaxf(infil - satexc, 0.0f);
    // frac^p_exp: frac==0 -> log2=-inf -> exp2(-inf)=0 (matches 0**p, p>=1)
    const float rech   = rem * EXP2F(p_exp * LOG2F(frac));
    const float evap3  = fminf(frac * Ept, S3);
    S3 = S3 + rem - rech - evap3;

    const float S4c   = fmaxf(S4, 0.0f);
    const float iflow = fminf(S4c, fmaf(i2, S4c * S4c, i1 * S4c));
    S4 = S4 + rech - iflow;

    const float base = kb * S5;
    S5 = S5 + iflow - base;

    float q = satexc + base;
    q += dpp_mov<DPP_XOR1>(q);
    q += dpp_mov<DPP_XOR2>(q);
    q += dpp_mov<DPP_HMIRR>(q);
    if ((lane & 55) == 0)                // m==0 && d==0: lanes 0 and 8
      Qs[bsel][t] = q * 0.125f;
  };

  // ---- depth-2 chunk pipeline; 1-step ping-pong register pipeline inside ----
  float r[2][12];
  ISSUE(0, 0);
  ISSUE(1, 1);
  for (int c = 0; c < NFULL; ++c) {
    asm volatile("s_waitcnt vmcnt(14)" ::: "memory");   // chunk c resident (c+1 in flight)
    const int buf = c & 1;
    const int t0  = c * CH;
    LOADR(buf, 0, r[0]);
    #pragma unroll
    for (int s = 0; s < CH; ++s) {
      if (s < CH - 1) LOADR(buf, s + 1, r[(s + 1) & 1]);
      STEPD(r[s & 1], t0 + s);
    }
    asm volatile("s_waitcnt lgkmcnt(0)" ::: "memory");  // reads of buf drained
    if (c + 2 < NCHUNK) ISSUE(c + 2, buf);
  }
  // tail chunk (c = 22): 13 valid steps, buf = 0
  asm volatile("s_waitcnt vmcnt(0)" ::: "memory");
  {
    const int t0 = NFULL * CH;           // 352
    LOADR(0, 0, r[0]);
    #pragma unroll
    for (int s = 0; s < 13; ++s) {
      if (s < 12) LOADR(0, s + 1, r[(s + 1) & 1]);
      STEPD(r[s & 1], t0 + s);
    }
  }

  __syncthreads();

  // ---- fused gamma routing conv, per basin (all 64 lanes) ----
  #pragma unroll
  for (int bs = 0; bs < 2; ++bs) {
    const float ra_v = bs ? ra1 : ra0;
    const float rb_v = bs ? rb1 : rb0;
    const float aa  = fmaxf(ra_v * 2.9f, 0.0f) + 0.1f;
    const float th  = fmaxf(rb_v * 6.5f, 0.0f) + 0.5f;
    const float am1 = aa - 1.0f;
    const float ith = -LOG2E / th;

    float w[LENF];
    float wsum = 0.0f;
    #pragma unroll
    for (int j = 0; j < LENF; ++j) {
      const float tj = (float)j + 0.5f;
      w[j] = EXP2F(fmaf(am1, LOG2F(tj), tj * ith));
      wsum += w[j];
    }
    const float inv = 1.0f / wsum;
    #pragma unroll
    for (int j = 0; j < LENF; ++j) w[j] *= inv;

    float* __restrict__ ob = out + (size_t)(b0 + bs) * NT;
    #pragma unroll
    for (int k = 0; k < 6; ++k) {
      const int t = lane + k * 64;
      if (t < NT) {
        float acc = 0.0f;
        #pragma unroll
        for (int j = 0; j < LENF; ++j) {
          const int idx = t - j;
          if (idx >= 0) acc += w[j] * Qs[bs][idx];
        }
        ob[t] = acc;
      }
    }
  }
}

extern "C" void kernel_launch(void* const* d_in, const int* in_sizes, int n_in,
                              void* d_out, int out_size, void* d_ws, size_t ws_size,
                              hipStream_t stream) {
  const float* P      = (const float*)d_in[0];
  const float* Ep     = (const float*)d_in[1];
  const float* Tair   = (const float*)d_in[2];
  const float* params = (const float*)d_in[3];
  const float* ra     = (const float*)d_in[4];
  const float* rb     = (const float*)d_in[5];
  float* out = (float*)d_out;

  prms_kernel<<<NB / 2, 64, 0, stream>>>(P, Ep, Tair, params, ra, rb, out);
}

// Round 14
// 77.727 us; speedup vs baseline: 1.3630x; 1.0707x over previous
//
#include <hip/hip_runtime.h>

#define NB      2000
#define NT      365
#define LENF    15
#define PSTRIDE 96              // 12 params * 8 muls, floats per (b,t)
#define CH      16              // timesteps per chunk
#define NFULL   22              // full chunks (352 steps)
#define NCHUNK  23              // incl. 13-step tail
#define CHBYTES (CH * PSTRIDE * 4)              // 6144 B per chunk per basin
#define BASIN_BYTES (NT * PSTRIDE * 4)          // 140160
#define CLAMP16     (BASIN_BYTES - 16)          // 140144
#define PARW    1544            // LDS words per basin param block (1536 + 8 pad; 1544%32==8)
#define FRCW    68              // LDS words per basin forcing block: 16 steps x 4 (P,Ep,T,pad) + 4
// VMEM ops per ISSUE = 12 GLD16 + 2 GLD4 = 14 -> main-loop wait is vmcnt(14)

#define GLD16(g, l) __builtin_amdgcn_global_load_lds( \
    (const __attribute__((address_space(1))) void*)(g), \
    (__attribute__((address_space(3))) void*)(l), 16, 0, 0)
#define GLD4(g, l) __builtin_amdgcn_global_load_lds( \
    (const __attribute__((address_space(1))) void*)(g), \
    (__attribute__((address_space(3))) void*)(l), 4, 0, 0)

#define EXP2F(x) __builtin_amdgcn_exp2f(x)
#define LOG2F(x) __builtin_amdgcn_logf(x)
#define LOG2E    1.44269504088896f

// DPP cross-lane ops — pure VALU, no LDS pipe, no lgkmcnt.
template <int CTRL>
__device__ __forceinline__ float dpp_mov(float x) {
  int xi = __float_as_int(x);
  int r  = __builtin_amdgcn_update_dpp(xi, xi, CTRL, 0xF, 0xF, true);
  return __int_as_float(r);
}
#define DPP_XOR1   0xB1    // quad_perm [1,0,3,2]
#define DPP_XOR2   0x4E    // quad_perm [2,3,0,1]
#define DPP_HMIRR  0x141   // row_half_mirror: i <-> 7-i within each 8-lane half

// TWO BASINS PER WAVE (lane = d*16 + bsel*8 + m), 1000 blocks -> ~4 waves/CU.
// R14 = R13 with DS-op count cut ~13 -> ~10.25/step:
//  (1) forcings staged as [s][4] float4 records -> 1 ds_read_b128 (was 3 b32)
//  (2) Q written 4x ds_read... ds_write_b128 per chunk (was 1 b32/step)
// Rationale: dur tracks chip DS work (R6->R7); wait-structure experiments
// (R8 batch vs R13 ping-pong) were null.
__global__ __launch_bounds__(64) void prms_kernel(
    const float* __restrict__ P, const float* __restrict__ Ep,
    const float* __restrict__ Tair, const float* __restrict__ params,
    const float* __restrict__ rout_a, const float* __restrict__ rout_b,
    float* __restrict__ out)
{
  __shared__ __attribute__((aligned(16))) float sh_par[2][2 * PARW];  // 24704 B
  __shared__ __attribute__((aligned(16))) float sh_frc[2][2][FRCW];   //  1088 B
  __shared__ __attribute__((aligned(16))) float Qs[2][NT + 3];        //  2944 B

  const int lane = threadIdx.x;        // 0..63
  const int m    = lane & 7;           // mul index
  const int bsel = (lane >> 3) & 1;    // which of the wave's 2 basins
  const int b0   = blockIdx.x * 2;     // first basin of this block

  // preload routing params early — latency hidden under the scan
  const float ra0 = rout_a[b0],     rb0 = rout_b[b0];
  const float ra1 = rout_a[b0 + 1], rb1 = rout_b[b0 + 1];

  const char* pbg[2] = {
    (const char*)(params + (size_t)b0 * (NT * PSTRIDE)),
    (const char*)(params + (size_t)(b0 + 1) * (NT * PSTRIDE)) };

  // forcing staging: lane -> (step fl_s = lane>>2, array fl_arr = lane&3);
  // arr 3 duplicates Tair into the pad word (never read)
  const int fl_s   = lane >> 2;
  const int fl_arr = (lane & 3) > 2 ? 2 : (lane & 3);
  const float* fsrcs[2][3] = {
    { P + (size_t)b0 * NT,       Ep + (size_t)b0 * NT,       Tair + (size_t)b0 * NT },
    { P + (size_t)(b0 + 1) * NT, Ep + (size_t)(b0 + 1) * NT, Tair + (size_t)(b0 + 1) * NT } };

  // ---- staging: 12x GLD16 (params) + 2x GLD4 (forcings) per chunk ----
  auto ISSUE = [&](int c, int buf) {
    #pragma unroll
    for (int bs = 0; bs < 2; ++bs) {
      #pragma unroll
      for (int j = 0; j < 6; ++j) {
        int off = c * CHBYTES + j * 1024 + lane * 16;
        off = off > CLAMP16 ? CLAMP16 : off;   // tail clamp (dups land in pad)
        GLD16(pbg[bs] + off, &sh_par[buf][bs * PARW + j * 256]);
      }
    }
    #pragma unroll
    for (int bs = 0; bs < 2; ++bs) {
      int ft = c * CH + fl_s;
      ft = ft > NT - 1 ? NT - 1 : ft;
      GLD4(fsrcs[bs][fl_arr] + ft, &sh_frc[buf][bs][0]);  // lane L -> word L = s*4+arr
    }
  };

  float S1 = 0.5f, S2 = 0.5f, S3 = 0.5f, S4 = 0.5f, S5 = 0.5f;
  const int pbase = bsel * PARW + m;    // thread-const param word base

  // ---- per-step LDS->register loads: 9 param b32 + 1 forcing b128 ----
  auto LOADR = [&](int buf, int s, float* r) {
    const float* par = &sh_par[buf][pbase + s * PSTRIDE];
    r[0] = par[0];   r[1] = par[8];   r[2] = par[24];
    r[3] = par[32];  r[4] = par[40];  r[5] = par[48];
    r[6] = par[64];  r[7] = par[72];  r[8] = par[80];
  };

  // returns this thread's reduced Q (valid on lanes 0,8 after DPP chain)
  auto STEPQ = [&](const float* d, float4 fv) -> float {
    const float tt    = fmaf(d[0], 8.0f, -3.0f);
    const float ddf   = d[1] * 20.0f;
    const float Smax3 = fmaf(d[2], 680.0f, 20.0f);
    const float p_lo  = fmaf(d[3], 0.99f, 0.005f);
    const float p_hi  = fmaf(d[4], 0.99f, 0.005f);
    const float p_exp = fmaf(d[5], 4.0f, 1.0f);
    const float i1    = d[6];
    const float i2    = d[7] * 0.001f;
    const float kb    = d[8];
    const float Pt    = fv.x;
    const float Ept   = fv.y;
    const float Tt    = fv.z;

    const float snow = (Tt <= tt) ? Pt : 0.0f;
    const float rain = Pt - snow;
    const float melt = fmaxf(fminf(ddf * (Tt - tt), S1), 0.0f);   // DT=1
    S1 = S1 + snow - melt;

    const float inter = rain * 0.95f;
    const float evap2 = fminf(S2, Ept);
    S2 = fmaxf(S2 + (rain - inter) - evap2, 0.0f);

    const float infil  = melt + inter;
    const float frac   = fmaxf(S3, 0.0f) * __builtin_amdgcn_rcpf(Smax3);
    const float satexc = (p_lo + (p_hi - p_lo) * frac) * infil;
    const float rem    = fmaxf(infil - satexc, 0.0f);
    // frac^p_exp: frac==0 -> log2=-inf -> exp2(-inf)=0 (matches 0**p, p>=1)
    const float rech   = rem * EXP2F(p_exp * LOG2F(frac));
    const float evap3  = fminf(frac * Ept, S3);
    S3 = S3 + rem - rech - evap3;

    const float S4c   = fmaxf(S4, 0.0f);
    const float iflow = fminf(S4c, fmaf(i2, S4c * S4c, i1 * S4c));
    S4 = S4 + rech - iflow;

    const float base = kb * S5;
    S5 = S5 + iflow - base;

    float q = satexc + base;
    q += dpp_mov<DPP_XOR1>(q);
    q += dpp_mov<DPP_XOR2>(q);
    q += dpp_mov<DPP_HMIRR>(q);
    return q * 0.125f;
  };

  // ---- depth-2 chunk pipeline; 1-step ping-pong; batched Q writes ----
  float r[2][9];
  float qv[CH];                          // statically indexed (unrolled s)
  ISSUE(0, 0);
  ISSUE(1, 1);
  for (int c = 0; c < NFULL; ++c) {
    asm volatile("s_waitcnt vmcnt(14)" ::: "memory");   // chunk c resident (c+1 in flight)
    const int buf = c & 1;
    const float4* fp = (const float4*)&sh_frc[buf][bsel][0];
    LOADR(buf, 0, r[0]);
    #pragma unroll
    for (int s = 0; s < CH; ++s) {
      if (s < CH - 1) LOADR(buf, s + 1, r[(s + 1) & 1]);
      qv[s] = STEPQ(r[s & 1], fp[s]);
    }
    if ((lane & 55) == 0) {              // lanes 0 (basin0) and 8 (basin1)
      const int t0 = c * CH;
      *(float4*)&Qs[bsel][t0]      = make_float4(qv[0],  qv[1],  qv[2],  qv[3]);
      *(float4*)&Qs[bsel][t0 + 4]  = make_float4(qv[4],  qv[5],  qv[6],  qv[7]);
      *(float4*)&Qs[bsel][t0 + 8]  = make_float4(qv[8],  qv[9],  qv[10], qv[11]);
      *(float4*)&Qs[bsel][t0 + 12] = make_float4(qv[12], qv[13], qv[14], qv[15]);
    }
    asm volatile("s_waitcnt lgkmcnt(0)" ::: "memory");  // reads of buf drained
    if (c + 2 < NCHUNK) ISSUE(c + 2, buf);
  }
  // tail chunk (c = 22): 13 valid steps, buf = 0
  asm volatile("s_waitcnt vmcnt(0)" ::: "memory");
  {
    const float4* fp = (const float4*)&sh_frc[0][bsel][0];
    LOADR(0, 0, r[0]);
    #pragma unroll
    for (int s = 0; s < 13; ++s) {
      if (s < 12) LOADR(0, s + 1, r[(s + 1) & 1]);
      qv[s] = STEPQ(r[s & 1], fp[s]);
    }
    if ((lane & 55) == 0) {
      *(float4*)&Qs[bsel][352] = make_float4(qv[0], qv[1], qv[2],  qv[3]);
      *(float4*)&Qs[bsel][356] = make_float4(qv[4], qv[5], qv[6],  qv[7]);
      *(float4*)&Qs[bsel][360] = make_float4(qv[8], qv[9], qv[10], qv[11]);
      Qs[bsel][364] = qv[12];
    }
  }

  __syncthreads();

  // ---- fused gamma routing conv, per basin (all 64 lanes) ----
  #pragma unroll
  for (int bs = 0; bs < 2; ++bs) {
    const float ra_v = bs ? ra1 : ra0;
    const float rb_v = bs ? rb1 : rb0;
    const float aa  = fmaxf(ra_v * 2.9f, 0.0f) + 0.1f;
    const float th  = fmaxf(rb_v * 6.5f, 0.0f) + 0.5f;
    const float am1 = aa - 1.0f;
    const float ith = -LOG2E / th;

    float w[LENF];
    float wsum = 0.0f;
    #pragma unroll
    for (int j = 0; j < LENF; ++j) {
      const float tj = (float)j + 0.5f;
      w[j] = EXP2F(fmaf(am1, LOG2F(tj), tj * ith));
      wsum += w[j];
    }
    const float inv = 1.0f / wsum;
    #pragma unroll
    for (int j = 0; j < LENF; ++j) w[j] *= inv;

    float* __restrict__ ob = out + (size_t)(b0 + bs) * NT;
    #pragma unroll
    for (int k = 0; k < 6; ++k) {
      const int t = lane + k * 64;
      if (t < NT) {
        float acc = 0.0f;
        #pragma unroll
        for (int j = 0; j < LENF; ++j) {
          const int idx = t - j;
          if (idx >= 0) acc += w[j] * Qs[bs][idx];
        }
        ob[t] = acc;
      }
    }
  }
}

extern "C" void kernel_launch(void* const* d_in, const int* in_sizes, int n_in,
                              void* d_out, int out_size, void* d_ws, size_t ws_size,
                              hipStream_t stream) {
  const float* P      = (const float*)d_in[0];
  const float* Ep     = (const float*)d_in[1];
  const float* Tair   = (const float*)d_in[2];
  const float* params = (const float*)d_in[3];
  const float* ra     = (const float*)d_in[4];
  const float* rb     = (const float*)d_in[5];
  float* out = (float*)d_out;

  prms_kernel<<<NB / 2, 64, 0, stream>>>(P, Ep, Tair, params, ra, rb, out);
}

// Round 15
// 75.258 us; speedup vs baseline: 1.4077x; 1.0328x over previous
//
#include <hip/hip_runtime.h>

#define NB      2000
#define NT      365
#define LENF    15
#define PSTRIDE 96              // 12 params * 8 muls, floats per (b,t)
#define CH      16              // timesteps per chunk
#define NFULL   22              // full chunks (352 steps)
#define NCHUNK  23              // incl. 13-step tail
#define CHBYTES (CH * PSTRIDE * 4)              // 6144 B per chunk per basin
#define BASIN_BYTES (NT * PSTRIDE * 4)          // 140160
#define CLAMP16     (BASIN_BYTES - 16)          // 140144
#define PARW    1544            // LDS words per basin param block (1536 + 8 pad; 1544%32==8)
#define FRCW    68              // LDS words per basin forcing block: 16 steps x 4 (P,Ep,T,pad) + 4
// VMEM ops per ISSUE = 12 GLD16 + 2 GLD4 = 14 -> main-loop wait is vmcnt(14)

#define GLD16(g, l) __builtin_amdgcn_global_load_lds( \
    (const __attribute__((address_space(1))) void*)(g), \
    (__attribute__((address_space(3))) void*)(l), 16, 0, 0)
#define GLD4(g, l) __builtin_amdgcn_global_load_lds( \
    (const __attribute__((address_space(1))) void*)(g), \
    (__attribute__((address_space(3))) void*)(l), 4, 0, 0)

#define EXP2F(x) __builtin_amdgcn_exp2f(x)
#define LOG2F(x) __builtin_amdgcn_logf(x)
#define LOG2E    1.44269504088896f

// DPP cross-lane ops — pure VALU, no LDS pipe, no lgkmcnt.
template <int CTRL>
__device__ __forceinline__ float dpp_mov(float x) {
  int xi = __float_as_int(x);
  int r  = __builtin_amdgcn_update_dpp(xi, xi, CTRL, 0xF, 0xF, true);
  return __int_as_float(r);
}
#define DPP_XOR1   0xB1    // quad_perm [1,0,3,2]
#define DPP_XOR2   0x4E    // quad_perm [2,3,0,1]
#define DPP_HMIRR  0x141   // row_half_mirror: i <-> 7-i within each 8-lane half

// TWO BASINS PER WAVE (lane = d*16 + bsel*8 + m), 1000 blocks -> ~4 waves/CU.
// R15 = R14 with the inner register pipeline deepened from 1-step ping-pong
// to a 3-slot rotation prefetching step s+2. Rationale: R14's 510cy/step =
// DS-pipe ~270 + VALU ~140 + ~100-150 of UNHIDDEN LDS round-trip (depth-1
// window 140cy < ~300cy queue+latency). With pair-merged param reads
// (ds_read2) ~6 DS ops/step, depth-2 = 12 outstanding <= lgkmcnt max 15.
__global__ __launch_bounds__(64) void prms_kernel(
    const float* __restrict__ P, const float* __restrict__ Ep,
    const float* __restrict__ Tair, const float* __restrict__ params,
    const float* __restrict__ rout_a, const float* __restrict__ rout_b,
    float* __restrict__ out)
{
  __shared__ __attribute__((aligned(16))) float sh_par[2][2 * PARW];  // 24704 B
  __shared__ __attribute__((aligned(16))) float sh_frc[2][2][FRCW];   //  1088 B
  __shared__ __attribute__((aligned(16))) float Qs[2][NT + 3];        //  2944 B

  const int lane = threadIdx.x;        // 0..63
  const int m    = lane & 7;           // mul index
  const int bsel = (lane >> 3) & 1;    // which of the wave's 2 basins
  const int b0   = blockIdx.x * 2;     // first basin of this block

  // preload routing params early — latency hidden under the scan
  const float ra0 = rout_a[b0],     rb0 = rout_b[b0];
  const float ra1 = rout_a[b0 + 1], rb1 = rout_b[b0 + 1];

  const char* pbg[2] = {
    (const char*)(params + (size_t)b0 * (NT * PSTRIDE)),
    (const char*)(params + (size_t)(b0 + 1) * (NT * PSTRIDE)) };

  // forcing staging: lane -> (step fl_s = lane>>2, array fl_arr = lane&3);
  // arr 3 duplicates Tair into the pad word (never read)
  const int fl_s   = lane >> 2;
  const int fl_arr = (lane & 3) > 2 ? 2 : (lane & 3);
  const float* fsrcs[2][3] = {
    { P + (size_t)b0 * NT,       Ep + (size_t)b0 * NT,       Tair + (size_t)b0 * NT },
    { P + (size_t)(b0 + 1) * NT, Ep + (size_t)(b0 + 1) * NT, Tair + (size_t)(b0 + 1) * NT } };

  // ---- staging: 12x GLD16 (params) + 2x GLD4 (forcings) per chunk ----
  auto ISSUE = [&](int c, int buf) {
    #pragma unroll
    for (int bs = 0; bs < 2; ++bs) {
      #pragma unroll
      for (int j = 0; j < 6; ++j) {
        int off = c * CHBYTES + j * 1024 + lane * 16;
        off = off > CLAMP16 ? CLAMP16 : off;   // tail clamp (dups land in pad)
        GLD16(pbg[bs] + off, &sh_par[buf][bs * PARW + j * 256]);
      }
    }
    #pragma unroll
    for (int bs = 0; bs < 2; ++bs) {
      int ft = c * CH + fl_s;
      ft = ft > NT - 1 ? NT - 1 : ft;
      GLD4(fsrcs[bs][fl_arr] + ft, &sh_frc[buf][bs][0]);  // lane L -> word L = s*4+arr
    }
  };

  float S1 = 0.5f, S2 = 0.5f, S3 = 0.5f, S4 = 0.5f, S5 = 0.5f;
  const int pbase = bsel * PARW + m;    // thread-const param word base

  // ---- per-step LDS->register loads: 9 param b32 (pair-mergeable) ----
  auto LOADR = [&](int buf, int s, float* r) {
    const float* par = &sh_par[buf][pbase + s * PSTRIDE];
    r[0] = par[0];   r[1] = par[8];   r[2] = par[24];
    r[3] = par[32];  r[4] = par[40];  r[5] = par[48];
    r[6] = par[64];  r[7] = par[72];  r[8] = par[80];
  };

  // returns this thread's reduced Q (valid on lanes 0,8 after DPP chain)
  auto STEPQ = [&](const float* d, float4 fv) -> float {
    const float tt    = fmaf(d[0], 8.0f, -3.0f);
    const float ddf   = d[1] * 20.0f;
    const float Smax3 = fmaf(d[2], 680.0f, 20.0f);
    const float p_lo  = fmaf(d[3], 0.99f, 0.005f);
    const float p_hi  = fmaf(d[4], 0.99f, 0.005f);
    const float p_exp = fmaf(d[5], 4.0f, 1.0f);
    const float i1    = d[6];
    const float i2    = d[7] * 0.001f;
    const float kb    = d[8];
    const float Pt    = fv.x;
    const float Ept   = fv.y;
    const float Tt    = fv.z;

    const float snow = (Tt <= tt) ? Pt : 0.0f;
    const float rain = Pt - snow;
    const float melt = fmaxf(fminf(ddf * (Tt - tt), S1), 0.0f);   // DT=1
    S1 = S1 + snow - melt;

    const float inter = rain * 0.95f;
    const float evap2 = fminf(S2, Ept);
    S2 = fmaxf(S2 + (rain - inter) - evap2, 0.0f);

    const float infil  = melt + inter;
    const float frac   = fmaxf(S3, 0.0f) * __builtin_amdgcn_rcpf(Smax3);
    const float satexc = (p_lo + (p_hi - p_lo) * frac) * infil;
    const float rem    = fmaxf(infil - satexc, 0.0f);
    // frac^p_exp: frac==0 -> log2=-inf -> exp2(-inf)=0 (matches 0**p, p>=1)
    const float rech   = rem * EXP2F(p_exp * LOG2F(frac));
    const float evap3  = fminf(frac * Ept, S3);
    S3 = S3 + rem - rech - evap3;

    const float S4c   = fmaxf(S4, 0.0f);
    const float iflow = fminf(S4c, fmaf(i2, S4c * S4c, i1 * S4c));
    S4 = S4 + rech - iflow;

    const float base = kb * S5;
    S5 = S5 + iflow - base;

    float q = satexc + base;
    q += dpp_mov<DPP_XOR1>(q);
    q += dpp_mov<DPP_XOR2>(q);
    q += dpp_mov<DPP_HMIRR>(q);
    return q * 0.125f;
  };

  // ---- depth-2 chunk pipeline; 3-slot (s+2) register rotation inside ----
  float r[3][9];
  float4 fv[3];
  float qv[CH];                          // statically indexed (unrolled s)
  ISSUE(0, 0);
  ISSUE(1, 1);
  for (int c = 0; c < NFULL; ++c) {
    asm volatile("s_waitcnt vmcnt(14)" ::: "memory");   // chunk c resident (c+1 in flight)
    const int buf = c & 1;
    const float4* fp = (const float4*)&sh_frc[buf][bsel][0];
    LOADR(buf, 0, r[0]); fv[0] = fp[0];
    LOADR(buf, 1, r[1]); fv[1] = fp[1];
    #pragma unroll
    for (int s = 0; s < CH; ++s) {
      if (s + 2 < CH) { LOADR(buf, s + 2, r[(s + 2) % 3]); fv[(s + 2) % 3] = fp[s + 2]; }
      qv[s] = STEPQ(r[s % 3], fv[s % 3]);
    }
    if ((lane & 55) == 0) {              // lanes 0 (basin0) and 8 (basin1)
      const int t0 = c * CH;
      *(float4*)&Qs[bsel][t0]      = make_float4(qv[0],  qv[1],  qv[2],  qv[3]);
      *(float4*)&Qs[bsel][t0 + 4]  = make_float4(qv[4],  qv[5],  qv[6],  qv[7]);
      *(float4*)&Qs[bsel][t0 + 8]  = make_float4(qv[8],  qv[9],  qv[10], qv[11]);
      *(float4*)&Qs[bsel][t0 + 12] = make_float4(qv[12], qv[13], qv[14], qv[15]);
    }
    asm volatile("s_waitcnt lgkmcnt(0)" ::: "memory");  // reads of buf drained
    if (c + 2 < NCHUNK) ISSUE(c + 2, buf);
  }
  // tail chunk (c = 22): 13 valid steps, buf = 0
  asm volatile("s_waitcnt vmcnt(0)" ::: "memory");
  {
    const float4* fp = (const float4*)&sh_frc[0][bsel][0];
    LOADR(0, 0, r[0]); fv[0] = fp[0];
    LOADR(0, 1, r[1]); fv[1] = fp[1];
    #pragma unroll
    for (int s = 0; s < 13; ++s) {
      if (s + 2 < 13) { LOADR(0, s + 2, r[(s + 2) % 3]); fv[(s + 2) % 3] = fp[s + 2]; }
      qv[s] = STEPQ(r[s % 3], fv[s % 3]);
    }
    if ((lane & 55) == 0) {
      *(float4*)&Qs[bsel][352] = make_float4(qv[0], qv[1], qv[2],  qv[3]);
      *(float4*)&Qs[bsel][356] = make_float4(qv[4], qv[5], qv[6],  qv[7]);
      *(float4*)&Qs[bsel][360] = make_float4(qv[8], qv[9], qv[10], qv[11]);
      Qs[bsel][364] = qv[12];
    }
  }

  __syncthreads();

  // ---- fused gamma routing conv, per basin (all 64 lanes) ----
  #pragma unroll
  for (int bs = 0; bs < 2; ++bs) {
    const float ra_v = bs ? ra1 : ra0;
    const float rb_v = bs ? rb1 : rb0;
    const float aa  = fmaxf(ra_v * 2.9f, 0.0f) + 0.1f;
    const float th  = fmaxf(rb_v * 6.5f, 0.0f) + 0.5f;
    const float am1 = aa - 1.0f;
    const float ith = -LOG2E / th;

    float w[LENF];
    float wsum = 0.0f;
    #pragma unroll
    for (int j = 0; j < LENF; ++j) {
      const float tj = (float)j + 0.5f;
      w[j] = EXP2F(fmaf(am1, LOG2F(tj), tj * ith));
      wsum += w[j];
    }
    const float inv = 1.0f / wsum;
    #pragma unroll
    for (int j = 0; j < LENF; ++j) w[j] *= inv;

    float* __restrict__ ob = out + (size_t)(b0 + bs) * NT;
    #pragma unroll
    for (int k = 0; k < 6; ++k) {
      const int t = lane + k * 64;
      if (t < NT) {
        float acc = 0.0f;
        #pragma unroll
        for (int j = 0; j < LENF; ++j) {
          const int idx = t - j;
          if (idx >= 0) acc += w[j] * Qs[bs][idx];
        }
        ob[t] = acc;
      }
    }
  }
}

extern "C" void kernel_launch(void* const* d_in, const int* in_sizes, int n_in,
                              void* d_out, int out_size, void* d_ws, size_t ws_size,
                              hipStream_t stream) {
  const float* P      = (const float*)d_in[0];
  const float* Ep     = (const float*)d_in[1];
  const float* Tair   = (const float*)d_in[2];
  const float* params = (const float*)d_in[3];
  const float* ra     = (const float*)d_in[4];
  const float* rb     = (const float*)d_in[5];
  float* out = (float*)d_out;

  prms_kernel<<<NB / 2, 64, 0, stream>>>(P, Ep, Tair, params, ra, rb, out);
}